// Round 16
// baseline (509.813 us; speedup 1.0000x reference)
//
#include <hip/hip_runtime.h>
#include <hip/hip_bf16.h>

#define DIM 256
#define QK 64
#define PD 128
#define HID 512
#define NPX 4096
#define NB 16
#define SCALE 0.125f
#define GN_EPS 1e-5f

typedef short bf16x8 __attribute__((ext_vector_type(8)));
typedef float f32x4 __attribute__((ext_vector_type(4)));
#define MFMA16(a, b, c) __builtin_amdgcn_mfma_f32_16x16x32_bf16(a, b, c, 0, 0, 0)

__device__ __forceinline__ unsigned f2b(float f) {
    unsigned u = __float_as_uint(f);
    return (u + 0x7fffu + ((u >> 16) & 1u)) >> 16;  // RNE bf16, low 16 bits
}
__device__ __forceinline__ float b2f(unsigned short s) {
    return __uint_as_float((unsigned)s << 16);
}

// ---------------- GroupNorm stats ----------------
__global__ __launch_bounds__(256) void gn_part_kernel(const float* __restrict__ x, float* __restrict__ part) {
    int chunk = blockIdx.x, b = blockIdx.y;
    const float* xp = x + (size_t)b * (DIM * NPX) + (size_t)chunk * 16384;
    float s = 0.f, ss = 0.f;
    for (int i = threadIdx.x; i < 16384; i += 256) { float v = xp[i]; s += v; ss += v * v; }
    for (int off = 32; off > 0; off >>= 1) { s += __shfl_down(s, off); ss += __shfl_down(ss, off); }
    __shared__ float red[8];
    int w = threadIdx.x >> 6;
    if ((threadIdx.x & 63) == 0) { red[w * 2] = s; red[w * 2 + 1] = ss; }
    __syncthreads();
    if (threadIdx.x == 0) {
        float S = red[0] + red[2] + red[4] + red[6];
        float SS = red[1] + red[3] + red[5] + red[7];
        part[(b * 64 + chunk) * 2] = S;
        part[(b * 64 + chunk) * 2 + 1] = SS;
    }
}

__global__ __launch_bounds__(256) void gn_final_kernel(const float* __restrict__ part,
                                                       const float* __restrict__ gn_w, const float* __restrict__ gn_b,
                                                       float* __restrict__ Aarr, float* __restrict__ Barr) {
    int b = blockIdx.x;
    float s = 0.f, ss = 0.f;
    if (threadIdx.x < 64) {
        s = part[(b * 64 + threadIdx.x) * 2];
        ss = part[(b * 64 + threadIdx.x) * 2 + 1];
        for (int off = 32; off > 0; off >>= 1) { s += __shfl_down(s, off); ss += __shfl_down(ss, off); }
    }
    __shared__ float sh[2];
    if (threadIdx.x == 0) {
        const float invN = 1.f / (float)(DIM * NPX);
        float mu = s * invN;
        float var = ss * invN - mu * mu;
        sh[0] = mu; sh[1] = rsqrtf(var + GN_EPS);
    }
    __syncthreads();
    float mu = sh[0], rstd = sh[1];
    int c = threadIdx.x;
    float g = gn_w[c] * rstd;
    Aarr[b * 256 + c] = g;
    Barr[b * 256 + c] = gn_b[c] - mu * g;
}

// ---------------- xn -> bf16 channels-last [B][64][64][256] ----------------
__global__ __launch_bounds__(256) void xnb_kernel(const float* __restrict__ x,
                                                  const float* __restrict__ Aarr, const float* __restrict__ Barr,
                                                  unsigned short* __restrict__ xb) {
    int y = blockIdx.x, b = blockIdx.y;
    int tid = threadIdx.x;
    __shared__ unsigned short tile[64 * 264];
    const float* xr = x + ((size_t)b << 20) + (size_t)y * 64;
    const float* Ab = Aarr + b * 256;
    const float* Bb = Barr + b * 256;
    for (int it = 0; it < 64; it++) {
        int lin = it * 256 + tid;
        int c = lin >> 6, px = lin & 63;
        float v = fmaf(xr[((size_t)c << 12) + px], Ab[c], Bb[c]);
        tile[px * 264 + c] = (unsigned short)f2b(v);
    }
    __syncthreads();
    unsigned short* ob = xb + (((size_t)(b * 64 + y)) << 14);
    for (int it = 0; it < 8; it++) {
        int lin = it * 256 + tid;
        int px = lin >> 5, g = lin & 31;
        *(uint4*)&ob[px * 256 + g * 8] = *(const uint4*)&tile[px * 264 + g * 8];
    }
}

// ---------------- weights -> bf16 ----------------
__global__ __launch_bounds__(256) void wcvt_kernel(const float* __restrict__ w_in, const float* __restrict__ w_out,
                                                   const float* __restrict__ w1, const float* __restrict__ w2,
                                                   unsigned short* __restrict__ wb2, unsigned short* __restrict__ wob,
                                                   unsigned short* __restrict__ w1b, unsigned short* __restrict__ w2b) {
    int idx = blockIdx.x * 256 + threadIdx.x;
    if (idx < 884736) {
        int ci = idx & 31;
        int oc = (idx >> 5) % 384;
        int tapck = idx / 12288;
        int ck = tapck / 9, tap = tapck % 9;
        wb2[idx] = (unsigned short)f2b(w_in[((size_t)oc * 256 + ck * 32 + ci) * 9 + tap]);
    } else if (idx < 950272) {
        int j = idx - 884736;
        wob[j] = (unsigned short)f2b(w_out[j]);
    } else if (idx < 1081344) {
        int j = idx - 950272;
        w1b[j] = (unsigned short)f2b(w1[j]);
    } else if (idx < 1212416) {
        int j = idx - 1081344;
        w2b[j] = (unsigned short)f2b(w2[j]);
    }
}

// ---------------- conv3x3 implicit-GEMM MFMA -> tcl [b][px][384] bf16 ----------------
// R12 tap loop (Af SB-prefetch, Bf just-in-time) + T14 async-STAGE split:
// ck+1's 6 staging loads issued right after ck's ds_write, hidden under MFMAs.
__global__ __launch_bounds__(256, 3) void conv3_mfma_kernel(const unsigned short* __restrict__ xb,
                                                            const unsigned short* __restrict__ wb2,
                                                            const float* __restrict__ s_in, const float* __restrict__ b_in,
                                                            unsigned short* __restrict__ tcl) {
    int wgid = blockIdx.x;
    int tile = (wgid & 7) * 96 + (wgid >> 3);
    int ocb = tile % 6;
    int tmp = tile / 6;          // 0..127
    int rg2 = tmp & 7, b = tmp >> 3;
    int tid = threadIdx.x;
    int w = tid >> 6, lane = tid & 63, g = lane >> 4, l15 = lane & 15;
    __shared__ unsigned short xs[6 * 66 * 40];
    int oc0 = ocb * 64;
    if (tid < 48) {
        int row = tid >> 3, cp = (tid >> 2) & 1, gg = tid & 3;
        int col = cp ? 65 : 0;
        *(uint4*)&xs[(row * 66 + col) * 40 + gg * 8] = make_uint4(0, 0, 0, 0);
    }
    const unsigned short* xg = xb + ((size_t)b << 20);  // [64][64][256]
    // per-thread staging coords (constant across stages)
    int sgg[6], scol[6], srow[6];
#pragma unroll
    for (int it = 0; it < 6; it++) {
        int lin = it * 256 + tid;
        sgg[it] = lin & 3; scol[it] = (lin >> 2) & 63; srow[it] = lin >> 8;
    }
    for (int half = 0; half < 2; half++) {
        int y0 = rg2 * 8 + half * 4;
        f32x4 acc[4][4];
#pragma unroll
        for (int o = 0; o < 4; o++)
#pragma unroll
            for (int p = 0; p < 4; p++)
#pragma unroll
                for (int r = 0; r < 4; r++) acc[o][p][r] = 0.f;
        // prologue: issue ck=0 staging loads
        uint4 stg[6];
#pragma unroll
        for (int it = 0; it < 6; it++) {
            int y = y0 - 1 + srow[it];
            stg[it] = make_uint4(0, 0, 0, 0);
            if (y >= 0 && y < 64)
                stg[it] = *(const uint4*)(xg + (((size_t)(y * 64 + scol[it])) << 8) + sgg[it] * 8);
        }
        for (int ck = 0; ck < 8; ck++) {
            __syncthreads();                 // all waves done reading xs (prev stage)
#pragma unroll
            for (int it = 0; it < 6; it++)   // ds_write current stage (waits vmcnt)
                *(uint4*)&xs[(srow[it] * 66 + scol[it] + 1) * 40 + sgg[it] * 8] = stg[it];
            __syncthreads();
            // issue next stage's loads — latency hides under the tap loop below
            if (ck < 7) {
                int ci0n = (ck + 1) * 32;
#pragma unroll
                for (int it = 0; it < 6; it++) {
                    int y = y0 - 1 + srow[it];
                    stg[it] = make_uint4(0, 0, 0, 0);
                    if (y >= 0 && y < 64)
                        stg[it] = *(const uint4*)(xg + (((size_t)(y * 64 + scol[it])) << 8) + ci0n + sgg[it] * 8);
                }
            }
            __builtin_amdgcn_sched_barrier(0);
            const unsigned short* wp = wb2 + (size_t)ck * 9 * 384 * 32;
            bf16x8 AfC[4], AfN[4];
#pragma unroll
            for (int o = 0; o < 4; o++)
                AfC[o] = *(const bf16x8*)(wp + ((size_t)0 * 384 + oc0 + o * 16 + l15) * 32 + g * 8);
#pragma unroll
            for (int tap = 0; tap < 9; tap++) {
                int dy = tap / 3, dx = tap % 3;
                if (tap < 8) {
#pragma unroll
                    for (int o = 0; o < 4; o++)
                        AfN[o] = *(const bf16x8*)(wp + ((size_t)(tap + 1) * 384 + oc0 + o * 16 + l15) * 32 + g * 8);
                }
                bf16x8 Bf[4];
#pragma unroll
                for (int p = 0; p < 4; p++)
                    Bf[p] = *(const bf16x8*)&xs[((w + dy) * 66 + p * 16 + l15 + dx) * 40 + g * 8];
                __builtin_amdgcn_sched_barrier(0);
#pragma unroll
                for (int o = 0; o < 4; o++)
#pragma unroll
                    for (int p = 0; p < 4; p++)
                        acc[o][p] = MFMA16(AfC[o], Bf[p], acc[o][p]);
                if (tap < 8) {
#pragma unroll
                    for (int o = 0; o < 4; o++) AfC[o] = AfN[o];
                }
            }
        }
        int y = y0 + w;
        unsigned short* tout = tcl + ((size_t)(b * 4096 + y * 64)) * 384;
#pragma unroll
        for (int o = 0; o < 4; o++) {
            int ocb4 = oc0 + o * 16 + 4 * g;
            float s0 = s_in[ocb4], s1 = s_in[ocb4 + 1], s2 = s_in[ocb4 + 2], s3 = s_in[ocb4 + 3];
            float b0 = b_in[ocb4], b1 = b_in[ocb4 + 1], b2 = b_in[ocb4 + 2], b3 = b_in[ocb4 + 3];
#pragma unroll
            for (int p = 0; p < 4; p++) {
                ushort4 h;
                h.x = (unsigned short)f2b(fmaf(acc[o][p][0], s0, b0));
                h.y = (unsigned short)f2b(fmaf(acc[o][p][1], s1, b1));
                h.z = (unsigned short)f2b(fmaf(acc[o][p][2], s2, b2));
                h.w = (unsigned short)f2b(fmaf(acc[o][p][3], s3, b3));
                *(ushort4*)&tout[(size_t)(p * 16 + l15) * 384 + ocb4] = h;
            }
        }
    }
}

// ---------------- depthwise 2x2 stride-2 (coalesced; v via LDS transpose) ----------------
__global__ __launch_bounds__(256) void dw_kernel(const unsigned short* __restrict__ tcl,
                                                 const float* __restrict__ w_k, const float* __restrict__ s_k, const float* __restrict__ b_k,
                                                 const float* __restrict__ w_v, const float* __restrict__ s_v, const float* __restrict__ b_v,
                                                 unsigned short* __restrict__ kd_t, unsigned short* __restrict__ vd_b) {
    int mg = blockIdx.x, b = blockIdx.y;
    int m0 = mg * 64;
    int tid = threadIdx.x;
    __shared__ unsigned short vt[128 * 68];
    {   // k-part
        int c = tid & 63;
        float4 wk4 = *(const float4*)(w_k + c * 4);
        float sc = s_k[c], bi = b_k[c];
#pragma unroll 4
        for (int it = 0; it < 16; it++) {
            int ml = it * 4 + (tid >> 6);
            int m = m0 + ml, yo = m >> 5, xo = m & 31;
            const unsigned short* s = tcl + ((size_t)(b * 4096 + yo * 128 + xo * 2)) * 384 + 64 + c;
            float v = wk4.x * b2f(s[0]) + wk4.y * b2f(s[384]) + wk4.z * b2f(s[24576]) + wk4.w * b2f(s[24960]);
            kd_t[((size_t)(b * 1024 + m) << 6) + c] = (unsigned short)f2b(fmaf(v, sc, bi));
        }
    }
    {   // v-part compute -> LDS [c][m], pad 68
        int c2 = tid & 127;
        float4 wv4 = *(const float4*)(w_v + c2 * 4);
        float sc = s_v[c2], bi = b_v[c2];
#pragma unroll 4
        for (int it = 0; it < 32; it++) {
            int ml = it * 2 + (tid >> 7);
            int m = m0 + ml, yo = m >> 5, xo = m & 31;
            const unsigned short* s = tcl + ((size_t)(b * 4096 + yo * 128 + xo * 2)) * 384 + 128 + c2;
            float v = wv4.x * b2f(s[0]) + wv4.y * b2f(s[384]) + wv4.z * b2f(s[24576]) + wv4.w * b2f(s[24960]);
            vt[c2 * 68 + ml] = (unsigned short)f2b(fmaf(v, sc, bi));
        }
    }
    __syncthreads();
    {   // v writeout
        int c2 = tid >> 1, part = tid & 1;
        unsigned short* dst = vd_b + (((size_t)(b * 128 + c2)) << 10) + m0 + part * 32;
        const unsigned short* src = &vt[c2 * 68 + part * 32];
#pragma unroll
        for (int j = 0; j < 8; j++)
            *(ushort4*)(dst + j * 4) = *(const ushort4*)(src + j * 4);
    }
}

// ---------------- MFMA flash attention: 16 q-rows/wave, KVBLK=64, 4 blocks/CU (R12) ----------------
__global__ __launch_bounds__(256, 4) void attn_mfma_kernel(const unsigned short* __restrict__ tcl,
                                                           const unsigned short* __restrict__ kd_t,
                                                           const unsigned short* __restrict__ vd_b,
                                                           unsigned short* __restrict__ apx) {
    int tid = threadIdx.x;
    int wid = tid >> 6, lane = tid & 63;
    int g = lane >> 4, l15 = lane & 15;
    int b = blockIdx.y;
    int n0 = (blockIdx.x * 4 + wid) * 16;

    __shared__ char smem[24576];
    char* KsB = smem;             // [64 m][128B row], slot-XOR (row&7)
    char* VsB = smem + 8192;      // [128 p][128B row], slot-XOR (row&7)

    const float SC2 = 0.18033688011112042f;   // 0.125 * log2(e)

    bf16x8 qf[2];
#pragma unroll
    for (int kc = 0; kc < 2; kc++)
        qf[kc] = *(const bf16x8*)(tcl + ((size_t)(b * 4096 + n0 + l15)) * 384 + kc * 32 + g * 8);

    f32x4 O[8];
#pragma unroll
    for (int pt = 0; pt < 8; pt++)
#pragma unroll
        for (int r = 0; r < 4; r++) O[pt][r] = 0.f;
    float mr = -1e30f, lr = 0.f;

    const unsigned short* kb = kd_t + ((size_t)b << 16);         // [1024 m][64 c]
    const unsigned short* vb = vd_b + ((size_t)(b * 128) << 10); // [128 p][1024 m]

    union BU { unsigned u[4]; bf16x8 v; };
    int srcA = l15 + ((g & 1) << 5);
    int srcB = srcA + 16;
    bool hi = (g >> 1) != 0;
    int srow8 = tid >> 3, sch8 = tid & 7;

    for (int mt = 0; mt < 16; mt++) {
        int m0 = mt * 64;
        __syncthreads();
#pragma unroll
        for (int it = 0; it < 2; it++) {          // K: 64 rows x 128B
            int row = it * 32 + srow8;
            uint4 v = *(const uint4*)(kb + (((size_t)(m0 + row)) << 6) + sch8 * 8);
            *(uint4*)(KsB + row * 128 + ((sch8 * 16) ^ ((row & 7) << 4))) = v;
        }
#pragma unroll
        for (int it = 0; it < 4; it++) {          // V: 128 rows x 128B
            int row = it * 32 + srow8;
            uint4 v = *(const uint4*)(vb + (((size_t)row) << 10) + m0 + sch8 * 8);
            *(uint4*)(VsB + row * 128 + ((sch8 * 16) ^ ((row & 7) << 4))) = v;
        }
        __syncthreads();
        f32x4 sp[4];
#pragma unroll
        for (int f = 0; f < 4; f++)
#pragma unroll
            for (int r = 0; r < 4; r++) sp[f][r] = 0.f;
#pragma unroll
        for (int f = 0; f < 4; f++) {
#pragma unroll
            for (int kc = 0; kc < 2; kc++) {
                bf16x8 kf = *(const bf16x8*)(KsB + (16 * f + l15) * 128 + ((kc * 64 + g * 16) ^ ((l15 & 7) << 4)));
                sp[f] = MFMA16(kf, qf[kc], sp[f]);
            }
        }
        float tmax = -1e30f;
#pragma unroll
        for (int f = 0; f < 4; f++)
#pragma unroll
            for (int r = 0; r < 4; r++) tmax = fmaxf(tmax, sp[f][r]);
        tmax = fmaxf(tmax, __shfl_xor(tmax, 16));
        tmax = fmaxf(tmax, __shfl_xor(tmax, 32));
        float tm2 = tmax * SC2;
        if (!__all(tm2 <= mr + 11.0f)) {
            float newm = fmaxf(mr, tm2);
            float fac = exp2f(mr - newm);
            lr *= fac;
#pragma unroll
            for (int pt = 0; pt < 8; pt++)
#pragma unroll
                for (int r = 0; r < 4; r++) O[pt][r] *= fac;
            mr = newm;
        }
        float ps = 0.f;
        unsigned pl[4], ph[4];
#pragma unroll
        for (int f = 0; f < 4; f++) {
            float p0 = exp2f(fmaf(sp[f][0], SC2, -mr));
            float p1 = exp2f(fmaf(sp[f][1], SC2, -mr));
            float p2 = exp2f(fmaf(sp[f][2], SC2, -mr));
            float p3 = exp2f(fmaf(sp[f][3], SC2, -mr));
            ps += (p0 + p1) + (p2 + p3);
            pl[f] = f2b(p0) | (f2b(p1) << 16);
            ph[f] = f2b(p2) | (f2b(p3) << 16);
        }
        ps += __shfl_xor(ps, 16);
        ps += __shfl_xor(ps, 32);
        lr += ps;
        BU Bp[2];
#pragma unroll
        for (int kc = 0; kc < 2; kc++) {
            unsigned a0 = (unsigned)__shfl((int)pl[2 * kc], srcA);
            unsigned a1 = (unsigned)__shfl((int)ph[2 * kc], srcA);
            unsigned b0 = (unsigned)__shfl((int)pl[2 * kc + 1], srcA);
            unsigned b1 = (unsigned)__shfl((int)ph[2 * kc + 1], srcA);
            unsigned a2 = (unsigned)__shfl((int)pl[2 * kc], srcB);
            unsigned a3 = (unsigned)__shfl((int)ph[2 * kc], srcB);
            unsigned b2 = (unsigned)__shfl((int)pl[2 * kc + 1], srcB);
            unsigned b3 = (unsigned)__shfl((int)ph[2 * kc + 1], srcB);
            Bp[kc].u[0] = hi ? b0 : a0;
            Bp[kc].u[1] = hi ? b1 : a1;
            Bp[kc].u[2] = hi ? b2 : a2;
            Bp[kc].u[3] = hi ? b3 : a3;
        }
#pragma unroll
        for (int pt = 0; pt < 8; pt++) {
            int p = pt * 16 + l15;
#pragma unroll
            for (int kc = 0; kc < 2; kc++) {
                bf16x8 vf = *(const bf16x8*)(VsB + p * 128 + ((kc * 64 + g * 16) ^ ((p & 7) << 4)));
                O[pt] = MFMA16(vf, Bp[kc].v, O[pt]);
            }
        }
    }
    __syncthreads();   // staging region dead; reuse as transpose tile
    unsigned short (*ot)[16][136] = (unsigned short (*)[16][136])smem;
    float inv = 1.f / lr;
#pragma unroll
    for (int pt = 0; pt < 8; pt++) {
#pragma unroll
        for (int r = 0; r < 4; r++) {
            int prow = pt * 16 + 4 * g + r;
            ot[wid][l15][prow] = (unsigned short)f2b(fmaxf(O[pt][r] * inv, 0.f));
        }
    }
#pragma unroll
    for (int j = 0; j < 4; j++) {
        int lin = j * 64 + lane;
        int row = lin >> 4, cg = lin & 15;
        *(uint4*)&apx[((size_t)(b * 4096 + n0 + row)) * 128 + cg * 8] = *(const uint4*)&ot[wid][row][cg * 8];
    }
}

// ---------------- catconv MFMA (plain): out = x + bn(W_out @ relu(cat)); emits x1cl ----------------
__global__ __launch_bounds__(256) void catconv_mfma_kernel(const unsigned short* __restrict__ apx,
                                                           const unsigned short* __restrict__ tcl,
                                                           const unsigned short* __restrict__ wob,
                                                           const float* __restrict__ x,
                                                           const float* __restrict__ s_out, const float* __restrict__ b_out,
                                                           float* __restrict__ out, unsigned short* __restrict__ x1cl) {
    int tid = threadIdx.x;
    int w = tid >> 6, lane = tid & 63, g = lane >> 4, l15 = lane & 15;
    int b = blockIdx.z;
    int px0 = blockIdx.x * 256 + w * 64;
    int co0 = blockIdx.y * 64;
    f32x4 acc[4][4];
#pragma unroll
    for (int o = 0; o < 4; o++)
#pragma unroll
        for (int p = 0; p < 4; p++)
#pragma unroll
            for (int r = 0; r < 4; r++) acc[o][p][r] = 0.f;
    const unsigned short* ab = apx + (((size_t)b * 4096) << 7);
    const unsigned short* ub = tcl + ((size_t)b * 4096) * 384 + 256;
    for (int kc = 0; kc < 8; kc++) {
        bf16x8 Af[4], Bf[4];
#pragma unroll
        for (int o = 0; o < 4; o++)
            Af[o] = *(const bf16x8*)(wob + (size_t)(co0 + o * 16 + l15) * 256 + kc * 32 + g * 8);
        if (kc < 4) {
#pragma unroll
            for (int p = 0; p < 4; p++)
                Bf[p] = *(const bf16x8*)(ab + ((size_t)(px0 + p * 16 + l15) << 7) + kc * 32 + g * 8);
        } else {
#pragma unroll
            for (int p = 0; p < 4; p++) {
                bf16x8 v = *(const bf16x8*)(ub + (size_t)(px0 + p * 16 + l15) * 384 + (kc - 4) * 32 + g * 8);
#pragma unroll
                for (int j = 0; j < 8; j++) {
                    unsigned short s = (unsigned short)v[j];
                    v[j] = (short)((s & 0x8000u) ? 0 : s);
                }
                Bf[p] = v;
            }
        }
#pragma unroll
        for (int o = 0; o < 4; o++)
#pragma unroll
            for (int p = 0; p < 4; p++)
                acc[o][p] = MFMA16(Af[o], Bf[p], acc[o][p]);
    }
#pragma unroll
    for (int o = 0; o < 4; o++) {
        int co_b = co0 + o * 16 + 4 * g;
#pragma unroll
        for (int r = 0; r < 4; r++) {
            int co = co_b + r;
            float sc = s_out[co], bi = b_out[co];
            size_t base = (((size_t)b * 256 + co) << 12) + px0 + l15;
#pragma unroll
            for (int p = 0; p < 4; p++) {
                float res = x[base + p * 16] + fmaf(acc[o][p][r], sc, bi);
                out[base + p * 16] = res;
                acc[o][p][r] = res;
            }
        }
#pragma unroll
        for (int p = 0; p < 4; p++) {
            ushort4 h;
            h.x = (unsigned short)f2b(acc[o][p][0]);
            h.y = (unsigned short)f2b(acc[o][p][1]);
            h.z = (unsigned short)f2b(acc[o][p][2]);
            h.w = (unsigned short)f2b(acc[o][p][3]);
            *(ushort4*)&x1cl[((size_t)(b * 4096 + px0 + p * 16 + l15)) * 256 + co_b] = h;
        }
    }
}

// ---------------- FFN1 MFMA (plain, swapped): hcl[px][hc] = relu(bn(W1 @ x1)) ----------------
__global__ __launch_bounds__(256) void ffn1_mfma_kernel(const unsigned short* __restrict__ x1cl,
                                                        const unsigned short* __restrict__ w1b,
                                                        const float* __restrict__ s1, const float* __restrict__ b1,
                                                        unsigned short* __restrict__ hcl) {
    int tid = threadIdx.x;
    int w = tid >> 6, lane = tid & 63, g = lane >> 4, l15 = lane & 15;
    int b = blockIdx.z;
    int px0 = blockIdx.x * 256 + w * 64;
    int hc0 = blockIdx.y * 64;
    f32x4 acc[4][4];  // [p][o]
#pragma unroll
    for (int p = 0; p < 4; p++)
#pragma unroll
        for (int o = 0; o < 4; o++)
#pragma unroll
            for (int r = 0; r < 4; r++) acc[p][o][r] = 0.f;
    const unsigned short* xb = x1cl + (((size_t)b * 4096) << 8);
    for (int kc = 0; kc < 8; kc++) {
        bf16x8 Af[4], Bf[4];
#pragma unroll
        for (int p = 0; p < 4; p++)
            Af[p] = *(const bf16x8*)(xb + ((size_t)(px0 + p * 16 + l15) << 8) + kc * 32 + g * 8);
#pragma unroll
        for (int o = 0; o < 4; o++)
            Bf[o] = *(const bf16x8*)(w1b + (size_t)(hc0 + o * 16 + l15) * 256 + kc * 32 + g * 8);
#pragma unroll
        for (int p = 0; p < 4; p++)
#pragma unroll
            for (int o = 0; o < 4; o++)
                acc[p][o] = MFMA16(Af[p], Bf[o], acc[p][o]);
    }
    unsigned short* hb = hcl + (((size_t)b * 4096) << 9);
#pragma unroll
    for (int o = 0; o < 4; o++) {
        int hc = hc0 + o * 16 + l15;
        float sc = s1[hc], bi = b1[hc];
#pragma unroll
        for (int p = 0; p < 4; p++) {
#pragma unroll
            for (int r = 0; r < 4; r++) {
                int px = px0 + p * 16 + 4 * g + r;
                hb[((size_t)px << 9) + hc] = (unsigned short)f2b(fmaxf(fmaf(acc[p][o][r], sc, bi), 0.f));
            }
        }
    }
}

// ---------------- FFN2 MFMA (plain): out += bn(W2 @ h) ----------------
__global__ __launch_bounds__(256) void ffn2_mfma_kernel(const unsigned short* __restrict__ hcl,
                                                        const unsigned short* __restrict__ w2b,
                                                        const float* __restrict__ s2, const float* __restrict__ b2,
                                                        float* __restrict__ out) {
    int tid = threadIdx.x;
    int w = tid >> 6, lane = tid & 63, g = lane >> 4, l15 = lane & 15;
    int b = blockIdx.z;
    int px0 = blockIdx.x * 256 + w * 64;
    int co0 = blockIdx.y * 64;
    f32x4 acc[4][4];
#pragma unroll
    for (int o = 0; o < 4; o++)
#pragma unroll
        for (int p = 0; p < 4; p++)
#pragma unroll
            for (int r = 0; r < 4; r++) acc[o][p][r] = 0.f;
    const unsigned short* hb = hcl + (((size_t)b * 4096) << 9);
    for (int kc = 0; kc < 16; kc++) {
        bf16x8 Af[4], Bf[4];
#pragma unroll
        for (int o = 0; o < 4; o++)
            Af[o] = *(const bf16x8*)(w2b + (size_t)(co0 + o * 16 + l15) * 512 + kc * 32 + g * 8);
#pragma unroll
        for (int p = 0; p < 4; p++)
            Bf[p] = *(const bf16x8*)(hb + ((size_t)(px0 + p * 16 + l15) << 9) + kc * 32 + g * 8);
#pragma unroll
        for (int o = 0; o < 4; o++)
#pragma unroll
            for (int p = 0; p < 4; p++)
                acc[o][p] = MFMA16(Af[o], Bf[p], acc[o][p]);
    }
#pragma unroll
    for (int o = 0; o < 4; o++) {
#pragma unroll
        for (int r = 0; r < 4; r++) {
            int co = co0 + o * 16 + 4 * g + r;
            float sc = s2[co], bi = b2[co];
            size_t base = (((size_t)b * 256 + co) << 12) + px0 + l15;
#pragma unroll
            for (int p = 0; p < 4; p++)
                out[base + p * 16] = out[base + p * 16] + fmaf(acc[o][p][r], sc, bi);
        }
    }
}

extern "C" void kernel_launch(void* const* d_in, const int* in_sizes, int n_in,
                              void* d_out, int out_size, void* d_ws, size_t ws_size,
                              hipStream_t stream) {
    const float* x    = (const float*)d_in[0];
    const float* gn_w = (const float*)d_in[1];
    const float* gn_b = (const float*)d_in[2];
    const float* w_in = (const float*)d_in[3];
    const float* s_in = (const float*)d_in[4];
    const float* b_in = (const float*)d_in[5];
    const float* w_k  = (const float*)d_in[6];
    const float* s_k  = (const float*)d_in[7];
    const float* b_k  = (const float*)d_in[8];
    const float* w_v  = (const float*)d_in[9];
    const float* s_v  = (const float*)d_in[10];
    const float* b_v  = (const float*)d_in[11];
    const float* w_out= (const float*)d_in[12];
    const float* s_out= (const float*)d_in[13];
    const float* b_out= (const float*)d_in[14];
    const float* w1   = (const float*)d_in[15];
    const float* s1   = (const float*)d_in[16];
    const float* b1   = (const float*)d_in[17];
    const float* w2   = (const float*)d_in[18];
    const float* s2   = (const float*)d_in[19];
    const float* b2   = (const float*)d_in[20];
    float* out = (float*)d_out;
    float* ws = (float*)d_ws;

    float* part = ws;                           // 2048
    float* Aarr = ws + 2048;
    float* Barr = ws + 6144;                    // end 10240
    unsigned short* tcl = (unsigned short*)(ws + 10240);       // 12,582,912 f -> end 12,593,152
    unsigned short* xb   = (unsigned short*)(ws + 12593152);
    unsigned short* x1cl = (unsigned short*)(ws + 12593152);
    unsigned short* apx  = (unsigned short*)(ws + 20981760);
    unsigned short* hcl  = (unsigned short*)(ws + 20981760);   // 33,554,432 sh -> end 37,758,976
    unsigned short* kd_t = (unsigned short*)(ws + 37758976);
    unsigned short* vd_b = (unsigned short*)(ws + 38283264);
    unsigned short* wb2  = (unsigned short*)(ws + 39331840);
    unsigned short* wob  = (unsigned short*)(ws + 39774208);
    unsigned short* w1b  = (unsigned short*)(ws + 39806976);
    unsigned short* w2b  = (unsigned short*)(ws + 39872512);

    gn_part_kernel<<<dim3(64, 16), 256, 0, stream>>>(x, part);
    gn_final_kernel<<<16, 256, 0, stream>>>(part, gn_w, gn_b, Aarr, Barr);
    xnb_kernel<<<dim3(64, 16), 256, 0, stream>>>(x, Aarr, Barr, xb);
    wcvt_kernel<<<4736, 256, 0, stream>>>(w_in, w_out, w1, w2, wb2, wob, w1b, w2b);
    conv3_mfma_kernel<<<768, 256, 0, stream>>>(xb, wb2, s_in, b_in, tcl);
    dw_kernel<<<dim3(16, 16), 256, 0, stream>>>(tcl, w_k, s_k, b_k, w_v, s_v, b_v, kd_t, vd_b);
    attn_mfma_kernel<<<dim3(64, 16), 256, 0, stream>>>(tcl, kd_t, vd_b, apx);
    catconv_mfma_kernel<<<dim3(16, 4, 16), 256, 0, stream>>>(apx, tcl, wob, x, s_out, b_out, out, x1cl);
    ffn1_mfma_kernel<<<dim3(16, 8, 16), 256, 0, stream>>>(x1cl, w1b, s1, b1, hcl);
    ffn2_mfma_kernel<<<dim3(16, 4, 16), 256, 0, stream>>>(hcl, w2b, s2, b2, out);
}

// Round 17
// 468.101 us; speedup vs baseline: 1.0891x; 1.0891x over previous
//
#include <hip/hip_runtime.h>
#include <hip/hip_bf16.h>

#define DIM 256
#define QK 64
#define PD 128
#define HID 512
#define NPX 4096
#define NB 16
#define SCALE 0.125f
#define GN_EPS 1e-5f

typedef short bf16x8 __attribute__((ext_vector_type(8)));
typedef float f32x4 __attribute__((ext_vector_type(4)));
#define MFMA16(a, b, c) __builtin_amdgcn_mfma_f32_16x16x32_bf16(a, b, c, 0, 0, 0)

__device__ __forceinline__ unsigned f2b(float f) {
    unsigned u = __float_as_uint(f);
    return (u + 0x7fffu + ((u >> 16) & 1u)) >> 16;  // RNE bf16, low 16 bits
}
__device__ __forceinline__ float b2f(unsigned short s) {
    return __uint_as_float((unsigned)s << 16);
}

// ---------------- GroupNorm stats ----------------
__global__ __launch_bounds__(256) void gn_part_kernel(const float* __restrict__ x, float* __restrict__ part) {
    int chunk = blockIdx.x, b = blockIdx.y;
    const float* xp = x + (size_t)b * (DIM * NPX) + (size_t)chunk * 16384;
    float s = 0.f, ss = 0.f;
    for (int i = threadIdx.x; i < 16384; i += 256) { float v = xp[i]; s += v; ss += v * v; }
    for (int off = 32; off > 0; off >>= 1) { s += __shfl_down(s, off); ss += __shfl_down(ss, off); }
    __shared__ float red[8];
    int w = threadIdx.x >> 6;
    if ((threadIdx.x & 63) == 0) { red[w * 2] = s; red[w * 2 + 1] = ss; }
    __syncthreads();
    if (threadIdx.x == 0) {
        float S = red[0] + red[2] + red[4] + red[6];
        float SS = red[1] + red[3] + red[5] + red[7];
        part[(b * 64 + chunk) * 2] = S;
        part[(b * 64 + chunk) * 2 + 1] = SS;
    }
}

__global__ __launch_bounds__(256) void gn_final_kernel(const float* __restrict__ part,
                                                       const float* __restrict__ gn_w, const float* __restrict__ gn_b,
                                                       float* __restrict__ Aarr, float* __restrict__ Barr) {
    int b = blockIdx.x;
    float s = 0.f, ss = 0.f;
    if (threadIdx.x < 64) {
        s = part[(b * 64 + threadIdx.x) * 2];
        ss = part[(b * 64 + threadIdx.x) * 2 + 1];
        for (int off = 32; off > 0; off >>= 1) { s += __shfl_down(s, off); ss += __shfl_down(ss, off); }
    }
    __shared__ float sh[2];
    if (threadIdx.x == 0) {
        const float invN = 1.f / (float)(DIM * NPX);
        float mu = s * invN;
        float var = ss * invN - mu * mu;
        sh[0] = mu; sh[1] = rsqrtf(var + GN_EPS);
    }
    __syncthreads();
    float mu = sh[0], rstd = sh[1];
    int c = threadIdx.x;
    float g = gn_w[c] * rstd;
    Aarr[b * 256 + c] = g;
    Barr[b * 256 + c] = gn_b[c] - mu * g;
}

// ---------------- xn -> bf16 channels-last [B][64][64][256] ----------------
__global__ __launch_bounds__(256) void xnb_kernel(const float* __restrict__ x,
                                                  const float* __restrict__ Aarr, const float* __restrict__ Barr,
                                                  unsigned short* __restrict__ xb) {
    int y = blockIdx.x, b = blockIdx.y;
    int tid = threadIdx.x;
    __shared__ unsigned short tile[64 * 264];
    const float* xr = x + ((size_t)b << 20) + (size_t)y * 64;
    const float* Ab = Aarr + b * 256;
    const float* Bb = Barr + b * 256;
    for (int it = 0; it < 64; it++) {
        int lin = it * 256 + tid;
        int c = lin >> 6, px = lin & 63;
        float v = fmaf(xr[((size_t)c << 12) + px], Ab[c], Bb[c]);
        tile[px * 264 + c] = (unsigned short)f2b(v);
    }
    __syncthreads();
    unsigned short* ob = xb + (((size_t)(b * 64 + y)) << 14);
    for (int it = 0; it < 8; it++) {
        int lin = it * 256 + tid;
        int px = lin >> 5, g = lin & 31;
        *(uint4*)&ob[px * 256 + g * 8] = *(const uint4*)&tile[px * 264 + g * 8];
    }
}

// ---------------- weights -> bf16 ----------------
__global__ __launch_bounds__(256) void wcvt_kernel(const float* __restrict__ w_in, const float* __restrict__ w_out,
                                                   const float* __restrict__ w1, const float* __restrict__ w2,
                                                   unsigned short* __restrict__ wb2, unsigned short* __restrict__ wob,
                                                   unsigned short* __restrict__ w1b, unsigned short* __restrict__ w2b) {
    int idx = blockIdx.x * 256 + threadIdx.x;
    if (idx < 884736) {
        int ci = idx & 31;
        int oc = (idx >> 5) % 384;
        int tapck = idx / 12288;
        int ck = tapck / 9, tap = tapck % 9;
        wb2[idx] = (unsigned short)f2b(w_in[((size_t)oc * 256 + ck * 32 + ci) * 9 + tap]);
    } else if (idx < 950272) {
        int j = idx - 884736;
        wob[j] = (unsigned short)f2b(w_out[j]);
    } else if (idx < 1081344) {
        int j = idx - 950272;
        w1b[j] = (unsigned short)f2b(w1[j]);
    } else if (idx < 1212416) {
        int j = idx - 1081344;
        w2b[j] = (unsigned short)f2b(w2[j]);
    }
}

// ---------------- conv3x3 implicit-GEMM MFMA -> tcl [b][px][384] bf16 (R12: best known) ----------------
// Af prefetch pinned with sched_barrier(0): tap t+1's 4 global weight loads are
// issued BEFORE tap t's 16 MFMAs and cannot be sunk below them.
__global__ __launch_bounds__(256, 3) void conv3_mfma_kernel(const unsigned short* __restrict__ xb,
                                                            const unsigned short* __restrict__ wb2,
                                                            const float* __restrict__ s_in, const float* __restrict__ b_in,
                                                            unsigned short* __restrict__ tcl) {
    int wgid = blockIdx.x;
    int tile = (wgid & 7) * 96 + (wgid >> 3);
    int ocb = tile % 6;
    int tmp = tile / 6;          // 0..127
    int rg2 = tmp & 7, b = tmp >> 3;
    int tid = threadIdx.x;
    int w = tid >> 6, lane = tid & 63, g = lane >> 4, l15 = lane & 15;
    __shared__ unsigned short xs[6 * 66 * 40];
    int oc0 = ocb * 64;
    if (tid < 48) {
        int row = tid >> 3, cp = (tid >> 2) & 1, gg = tid & 3;
        int col = cp ? 65 : 0;
        *(uint4*)&xs[(row * 66 + col) * 40 + gg * 8] = make_uint4(0, 0, 0, 0);
    }
    const unsigned short* xg = xb + ((size_t)b << 20);  // [64][64][256]
    for (int half = 0; half < 2; half++) {
        int y0 = rg2 * 8 + half * 4;
        f32x4 acc[4][4];
#pragma unroll
        for (int o = 0; o < 4; o++)
#pragma unroll
            for (int p = 0; p < 4; p++)
#pragma unroll
                for (int r = 0; r < 4; r++) acc[o][p][r] = 0.f;
        for (int ck = 0; ck < 8; ck++) {
            int ci0 = ck * 32;
            __syncthreads();
#pragma unroll
            for (int it = 0; it < 6; it++) {
                int lin = it * 256 + tid;
                int gg = lin & 3, col = (lin >> 2) & 63, row = lin >> 8;
                int y = y0 - 1 + row;
                uint4 val = make_uint4(0, 0, 0, 0);
                if (y >= 0 && y < 64)
                    val = *(const uint4*)(xg + (((size_t)(y * 64 + col)) << 8) + ci0 + gg * 8);
                *(uint4*)&xs[(row * 66 + col + 1) * 40 + gg * 8] = val;
            }
            __syncthreads();
            const unsigned short* wp = wb2 + (size_t)ck * 9 * 384 * 32;
            bf16x8 AfC[4], AfN[4];
#pragma unroll
            for (int o = 0; o < 4; o++)
                AfC[o] = *(const bf16x8*)(wp + ((size_t)0 * 384 + oc0 + o * 16 + l15) * 32 + g * 8);
#pragma unroll
            for (int tap = 0; tap < 9; tap++) {
                int dy = tap / 3, dx = tap % 3;
                if (tap < 8) {
#pragma unroll
                    for (int o = 0; o < 4; o++)
                        AfN[o] = *(const bf16x8*)(wp + ((size_t)(tap + 1) * 384 + oc0 + o * 16 + l15) * 32 + g * 8);
                }
                bf16x8 Bf[4];
#pragma unroll
                for (int p = 0; p < 4; p++)
                    Bf[p] = *(const bf16x8*)&xs[((w + dy) * 66 + p * 16 + l15 + dx) * 40 + g * 8];
                __builtin_amdgcn_sched_barrier(0);
#pragma unroll
                for (int o = 0; o < 4; o++)
#pragma unroll
                    for (int p = 0; p < 4; p++)
                        acc[o][p] = MFMA16(AfC[o], Bf[p], acc[o][p]);
                if (tap < 8) {
#pragma unroll
                    for (int o = 0; o < 4; o++) AfC[o] = AfN[o];
                }
            }
        }
        int y = y0 + w;
        unsigned short* tout = tcl + ((size_t)(b * 4096 + y * 64)) * 384;
#pragma unroll
        for (int o = 0; o < 4; o++) {
            int ocb4 = oc0 + o * 16 + 4 * g;
            float s0 = s_in[ocb4], s1 = s_in[ocb4 + 1], s2 = s_in[ocb4 + 2], s3 = s_in[ocb4 + 3];
            float b0 = b_in[ocb4], b1 = b_in[ocb4 + 1], b2 = b_in[ocb4 + 2], b3 = b_in[ocb4 + 3];
#pragma unroll
            for (int p = 0; p < 4; p++) {
                ushort4 h;
                h.x = (unsigned short)f2b(fmaf(acc[o][p][0], s0, b0));
                h.y = (unsigned short)f2b(fmaf(acc[o][p][1], s1, b1));
                h.z = (unsigned short)f2b(fmaf(acc[o][p][2], s2, b2));
                h.w = (unsigned short)f2b(fmaf(acc[o][p][3], s3, b3));
                *(ushort4*)&tout[(size_t)(p * 16 + l15) * 384 + ocb4] = h;
            }
        }
    }
}

// ---------------- depthwise 2x2 stride-2 (coalesced; v via LDS transpose) ----------------
__global__ __launch_bounds__(256) void dw_kernel(const unsigned short* __restrict__ tcl,
                                                 const float* __restrict__ w_k, const float* __restrict__ s_k, const float* __restrict__ b_k,
                                                 const float* __restrict__ w_v, const float* __restrict__ s_v, const float* __restrict__ b_v,
                                                 unsigned short* __restrict__ kd_t, unsigned short* __restrict__ vd_b) {
    int mg = blockIdx.x, b = blockIdx.y;
    int m0 = mg * 64;
    int tid = threadIdx.x;
    __shared__ unsigned short vt[128 * 68];
    {   // k-part
        int c = tid & 63;
        float4 wk4 = *(const float4*)(w_k + c * 4);
        float sc = s_k[c], bi = b_k[c];
#pragma unroll 4
        for (int it = 0; it < 16; it++) {
            int ml = it * 4 + (tid >> 6);
            int m = m0 + ml, yo = m >> 5, xo = m & 31;
            const unsigned short* s = tcl + ((size_t)(b * 4096 + yo * 128 + xo * 2)) * 384 + 64 + c;
            float v = wk4.x * b2f(s[0]) + wk4.y * b2f(s[384]) + wk4.z * b2f(s[24576]) + wk4.w * b2f(s[24960]);
            kd_t[((size_t)(b * 1024 + m) << 6) + c] = (unsigned short)f2b(fmaf(v, sc, bi));
        }
    }
    {   // v-part compute -> LDS [c][m], pad 68
        int c2 = tid & 127;
        float4 wv4 = *(const float4*)(w_v + c2 * 4);
        float sc = s_v[c2], bi = b_v[c2];
#pragma unroll 4
        for (int it = 0; it < 32; it++) {
            int ml = it * 2 + (tid >> 7);
            int m = m0 + ml, yo = m >> 5, xo = m & 31;
            const unsigned short* s = tcl + ((size_t)(b * 4096 + yo * 128 + xo * 2)) * 384 + 128 + c2;
            float v = wv4.x * b2f(s[0]) + wv4.y * b2f(s[384]) + wv4.z * b2f(s[24576]) + wv4.w * b2f(s[24960]);
            vt[c2 * 68 + ml] = (unsigned short)f2b(fmaf(v, sc, bi));
        }
    }
    __syncthreads();
    {   // v writeout
        int c2 = tid >> 1, part = tid & 1;
        unsigned short* dst = vd_b + (((size_t)(b * 128 + c2)) << 10) + m0 + part * 32;
        const unsigned short* src = &vt[c2 * 68 + part * 32];
#pragma unroll
        for (int j = 0; j < 8; j++)
            *(ushort4*)(dst + j * 4) = *(const ushort4*)(src + j * 4);
    }
}

// ---------------- MFMA flash attention: 16 q-rows/wave, KVBLK=64, 4 blocks/CU ----------------
__global__ __launch_bounds__(256, 4) void attn_mfma_kernel(const unsigned short* __restrict__ tcl,
                                                           const unsigned short* __restrict__ kd_t,
                                                           const unsigned short* __restrict__ vd_b,
                                                           unsigned short* __restrict__ apx) {
    int tid = threadIdx.x;
    int wid = tid >> 6, lane = tid & 63;
    int g = lane >> 4, l15 = lane & 15;
    int b = blockIdx.y;
    int n0 = (blockIdx.x * 4 + wid) * 16;

    __shared__ char smem[24576];
    char* KsB = smem;             // [64 m][128B row], slot-XOR (row&7)
    char* VsB = smem + 8192;      // [128 p][128B row], slot-XOR (row&7)

    const float SC2 = 0.18033688011112042f;   // 0.125 * log2(e)

    bf16x8 qf[2];
#pragma unroll
    for (int kc = 0; kc < 2; kc++)
        qf[kc] = *(const bf16x8*)(tcl + ((size_t)(b * 4096 + n0 + l15)) * 384 + kc * 32 + g * 8);

    f32x4 O[8];
#pragma unroll
    for (int pt = 0; pt < 8; pt++)
#pragma unroll
        for (int r = 0; r < 4; r++) O[pt][r] = 0.f;
    float mr = -1e30f, lr = 0.f;

    const unsigned short* kb = kd_t + ((size_t)b << 16);         // [1024 m][64 c]
    const unsigned short* vb = vd_b + ((size_t)(b * 128) << 10); // [128 p][1024 m]

    union BU { unsigned u[4]; bf16x8 v; };
    int srcA = l15 + ((g & 1) << 5);
    int srcB = srcA + 16;
    bool hi = (g >> 1) != 0;
    int srow8 = tid >> 3, sch8 = tid & 7;

    for (int mt = 0; mt < 16; mt++) {
        int m0 = mt * 64;
        __syncthreads();
#pragma unroll
        for (int it = 0; it < 2; it++) {          // K: 64 rows x 128B
            int row = it * 32 + srow8;
            uint4 v = *(const uint4*)(kb + (((size_t)(m0 + row)) << 6) + sch8 * 8);
            *(uint4*)(KsB + row * 128 + ((sch8 * 16) ^ ((row & 7) << 4))) = v;
        }
#pragma unroll
        for (int it = 0; it < 4; it++) {          // V: 128 rows x 128B
            int row = it * 32 + srow8;
            uint4 v = *(const uint4*)(vb + (((size_t)row) << 10) + m0 + sch8 * 8);
            *(uint4*)(VsB + row * 128 + ((sch8 * 16) ^ ((row & 7) << 4))) = v;
        }
        __syncthreads();
        f32x4 sp[4];
#pragma unroll
        for (int f = 0; f < 4; f++)
#pragma unroll
            for (int r = 0; r < 4; r++) sp[f][r] = 0.f;
#pragma unroll
        for (int f = 0; f < 4; f++) {
#pragma unroll
            for (int kc = 0; kc < 2; kc++) {
                bf16x8 kf = *(const bf16x8*)(KsB + (16 * f + l15) * 128 + ((kc * 64 + g * 16) ^ ((l15 & 7) << 4)));
                sp[f] = MFMA16(kf, qf[kc], sp[f]);
            }
        }
        float tmax = -1e30f;
#pragma unroll
        for (int f = 0; f < 4; f++)
#pragma unroll
            for (int r = 0; r < 4; r++) tmax = fmaxf(tmax, sp[f][r]);
        tmax = fmaxf(tmax, __shfl_xor(tmax, 16));
        tmax = fmaxf(tmax, __shfl_xor(tmax, 32));
        float tm2 = tmax * SC2;
        if (!__all(tm2 <= mr + 11.0f)) {
            float newm = fmaxf(mr, tm2);
            float fac = exp2f(mr - newm);
            lr *= fac;
#pragma unroll
            for (int pt = 0; pt < 8; pt++)
#pragma unroll
                for (int r = 0; r < 4; r++) O[pt][r] *= fac;
            mr = newm;
        }
        float ps = 0.f;
        unsigned pl[4], ph[4];
#pragma unroll
        for (int f = 0; f < 4; f++) {
            float p0 = exp2f(fmaf(sp[f][0], SC2, -mr));
            float p1 = exp2f(fmaf(sp[f][1], SC2, -mr));
            float p2 = exp2f(fmaf(sp[f][2], SC2, -mr));
            float p3 = exp2f(fmaf(sp[f][3], SC2, -mr));
            ps += (p0 + p1) + (p2 + p3);
            pl[f] = f2b(p0) | (f2b(p1) << 16);
            ph[f] = f2b(p2) | (f2b(p3) << 16);
        }
        ps += __shfl_xor(ps, 16);
        ps += __shfl_xor(ps, 32);
        lr += ps;
        BU Bp[2];
#pragma unroll
        for (int kc = 0; kc < 2; kc++) {
            unsigned a0 = (unsigned)__shfl((int)pl[2 * kc], srcA);
            unsigned a1 = (unsigned)__shfl((int)ph[2 * kc], srcA);
            unsigned b0 = (unsigned)__shfl((int)pl[2 * kc + 1], srcA);
            unsigned b1 = (unsigned)__shfl((int)ph[2 * kc + 1], srcA);
            unsigned a2 = (unsigned)__shfl((int)pl[2 * kc], srcB);
            unsigned a3 = (unsigned)__shfl((int)ph[2 * kc], srcB);
            unsigned b2 = (unsigned)__shfl((int)pl[2 * kc + 1], srcB);
            unsigned b3 = (unsigned)__shfl((int)ph[2 * kc + 1], srcB);
            Bp[kc].u[0] = hi ? b0 : a0;
            Bp[kc].u[1] = hi ? b1 : a1;
            Bp[kc].u[2] = hi ? b2 : a2;
            Bp[kc].u[3] = hi ? b3 : a3;
        }
#pragma unroll
        for (int pt = 0; pt < 8; pt++) {
            int p = pt * 16 + l15;
#pragma unroll
            for (int kc = 0; kc < 2; kc++) {
                bf16x8 vf = *(const bf16x8*)(VsB + p * 128 + ((kc * 64 + g * 16) ^ ((p & 7) << 4)));
                O[pt] = MFMA16(vf, Bp[kc].v, O[pt]);
            }
        }
    }
    __syncthreads();   // staging region dead; reuse as transpose tile
    unsigned short (*ot)[16][136] = (unsigned short (*)[16][136])smem;
    float inv = 1.f / lr;
#pragma unroll
    for (int pt = 0; pt < 8; pt++) {
#pragma unroll
        for (int r = 0; r < 4; r++) {
            int prow = pt * 16 + 4 * g + r;
            ot[wid][l15][prow] = (unsigned short)f2b(fmaxf(O[pt][r] * inv, 0.f));
        }
    }
#pragma unroll
    for (int j = 0; j < 4; j++) {
        int lin = j * 64 + lane;
        int row = lin >> 4, cg = lin & 15;
        *(uint4*)&apx[((size_t)(b * 4096 + n0 + row)) * 128 + cg * 8] = *(const uint4*)&ot[wid][row][cg * 8];
    }
}

// ---------------- catconv MFMA (plain): out = x + bn(W_out @ relu(cat)); emits x1cl ----------------
__global__ __launch_bounds__(256) void catconv_mfma_kernel(const unsigned short* __restrict__ apx,
                                                           const unsigned short* __restrict__ tcl,
                                                           const unsigned short* __restrict__ wob,
                                                           const float* __restrict__ x,
                                                           const float* __restrict__ s_out, const float* __restrict__ b_out,
                                                           float* __restrict__ out, unsigned short* __restrict__ x1cl) {
    int tid = threadIdx.x;
    int w = tid >> 6, lane = tid & 63, g = lane >> 4, l15 = lane & 15;
    int b = blockIdx.z;
    int px0 = blockIdx.x * 256 + w * 64;
    int co0 = blockIdx.y * 64;
    f32x4 acc[4][4];
#pragma unroll
    for (int o = 0; o < 4; o++)
#pragma unroll
        for (int p = 0; p < 4; p++)
#pragma unroll
            for (int r = 0; r < 4; r++) acc[o][p][r] = 0.f;
    const unsigned short* ab = apx + (((size_t)b * 4096) << 7);
    const unsigned short* ub = tcl + ((size_t)b * 4096) * 384 + 256;
    for (int kc = 0; kc < 8; kc++) {
        bf16x8 Af[4], Bf[4];
#pragma unroll
        for (int o = 0; o < 4; o++)
            Af[o] = *(const bf16x8*)(wob + (size_t)(co0 + o * 16 + l15) * 256 + kc * 32 + g * 8);
        if (kc < 4) {
#pragma unroll
            for (int p = 0; p < 4; p++)
                Bf[p] = *(const bf16x8*)(ab + ((size_t)(px0 + p * 16 + l15) << 7) + kc * 32 + g * 8);
        } else {
#pragma unroll
            for (int p = 0; p < 4; p++) {
                bf16x8 v = *(const bf16x8*)(ub + (size_t)(px0 + p * 16 + l15) * 384 + (kc - 4) * 32 + g * 8);
#pragma unroll
                for (int j = 0; j < 8; j++) {
                    unsigned short s = (unsigned short)v[j];
                    v[j] = (short)((s & 0x8000u) ? 0 : s);
                }
                Bf[p] = v;
            }
        }
#pragma unroll
        for (int o = 0; o < 4; o++)
#pragma unroll
            for (int p = 0; p < 4; p++)
                acc[o][p] = MFMA16(Af[o], Bf[p], acc[o][p]);
    }
#pragma unroll
    for (int o = 0; o < 4; o++) {
        int co_b = co0 + o * 16 + 4 * g;
#pragma unroll
        for (int r = 0; r < 4; r++) {
            int co = co_b + r;
            float sc = s_out[co], bi = b_out[co];
            size_t base = (((size_t)b * 256 + co) << 12) + px0 + l15;
#pragma unroll
            for (int p = 0; p < 4; p++) {
                float res = x[base + p * 16] + fmaf(acc[o][p][r], sc, bi);
                out[base + p * 16] = res;
                acc[o][p][r] = res;
            }
        }
#pragma unroll
        for (int p = 0; p < 4; p++) {
            ushort4 h;
            h.x = (unsigned short)f2b(acc[o][p][0]);
            h.y = (unsigned short)f2b(acc[o][p][1]);
            h.z = (unsigned short)f2b(acc[o][p][2]);
            h.w = (unsigned short)f2b(acc[o][p][3]);
            *(ushort4*)&x1cl[((size_t)(b * 4096 + px0 + p * 16 + l15)) * 256 + co_b] = h;
        }
    }
}

// ---------------- FFN1 MFMA (plain, swapped): hcl[px][hc] = relu(bn(W1 @ x1)) ----------------
__global__ __launch_bounds__(256) void ffn1_mfma_kernel(const unsigned short* __restrict__ x1cl,
                                                        const unsigned short* __restrict__ w1b,
                                                        const float* __restrict__ s1, const float* __restrict__ b1,
                                                        unsigned short* __restrict__ hcl) {
    int tid = threadIdx.x;
    int w = tid >> 6, lane = tid & 63, g = lane >> 4, l15 = lane & 15;
    int b = blockIdx.z;
    int px0 = blockIdx.x * 256 + w * 64;
    int hc0 = blockIdx.y * 64;
    f32x4 acc[4][4];  // [p][o]
#pragma unroll
    for (int p = 0; p < 4; p++)
#pragma unroll
        for (int o = 0; o < 4; o++)
#pragma unroll
            for (int r = 0; r < 4; r++) acc[p][o][r] = 0.f;
    const unsigned short* xb = x1cl + (((size_t)b * 4096) << 8);
    for (int kc = 0; kc < 8; kc++) {
        bf16x8 Af[4], Bf[4];
#pragma unroll
        for (int p = 0; p < 4; p++)
            Af[p] = *(const bf16x8*)(xb + ((size_t)(px0 + p * 16 + l15) << 8) + kc * 32 + g * 8);
#pragma unroll
        for (int o = 0; o < 4; o++)
            Bf[o] = *(const bf16x8*)(w1b + (size_t)(hc0 + o * 16 + l15) * 256 + kc * 32 + g * 8);
#pragma unroll
        for (int p = 0; p < 4; p++)
#pragma unroll
            for (int o = 0; o < 4; o++)
                acc[p][o] = MFMA16(Af[p], Bf[o], acc[p][o]);
    }
    unsigned short* hb = hcl + (((size_t)b * 4096) << 9);
#pragma unroll
    for (int o = 0; o < 4; o++) {
        int hc = hc0 + o * 16 + l15;
        float sc = s1[hc], bi = b1[hc];
#pragma unroll
        for (int p = 0; p < 4; p++) {
#pragma unroll
            for (int r = 0; r < 4; r++) {
                int px = px0 + p * 16 + 4 * g + r;
                hb[((size_t)px << 9) + hc] = (unsigned short)f2b(fmaxf(fmaf(acc[p][o][r], sc, bi), 0.f));
            }
        }
    }
}

// ---------------- FFN2 MFMA (plain): out += bn(W2 @ h) ----------------
__global__ __launch_bounds__(256) void ffn2_mfma_kernel(const unsigned short* __restrict__ hcl,
                                                        const unsigned short* __restrict__ w2b,
                                                        const float* __restrict__ s2, const float* __restrict__ b2,
                                                        float* __restrict__ out) {
    int tid = threadIdx.x;
    int w = tid >> 6, lane = tid & 63, g = lane >> 4, l15 = lane & 15;
    int b = blockIdx.z;
    int px0 = blockIdx.x * 256 + w * 64;
    int co0 = blockIdx.y * 64;
    f32x4 acc[4][4];
#pragma unroll
    for (int o = 0; o < 4; o++)
#pragma unroll
        for (int p = 0; p < 4; p++)
#pragma unroll
            for (int r = 0; r < 4; r++) acc[o][p][r] = 0.f;
    const unsigned short* hb = hcl + (((size_t)b * 4096) << 9);
    for (int kc = 0; kc < 16; kc++) {
        bf16x8 Af[4], Bf[4];
#pragma unroll
        for (int o = 0; o < 4; o++)
            Af[o] = *(const bf16x8*)(w2b + (size_t)(co0 + o * 16 + l15) * 512 + kc * 32 + g * 8);
#pragma unroll
        for (int p = 0; p < 4; p++)
            Bf[p] = *(const bf16x8*)(hb + ((size_t)(px0 + p * 16 + l15) << 9) + kc * 32 + g * 8);
#pragma unroll
        for (int o = 0; o < 4; o++)
#pragma unroll
            for (int p = 0; p < 4; p++)
                acc[o][p] = MFMA16(Af[o], Bf[p], acc[o][p]);
    }
#pragma unroll
    for (int o = 0; o < 4; o++) {
#pragma unroll
        for (int r = 0; r < 4; r++) {
            int co = co0 + o * 16 + 4 * g + r;
            float sc = s2[co], bi = b2[co];
            size_t base = (((size_t)b * 256 + co) << 12) + px0 + l15;
#pragma unroll
            for (int p = 0; p < 4; p++)
                out[base + p * 16] = out[base + p * 16] + fmaf(acc[o][p][r], sc, bi);
        }
    }
}

extern "C" void kernel_launch(void* const* d_in, const int* in_sizes, int n_in,
                              void* d_out, int out_size, void* d_ws, size_t ws_size,
                              hipStream_t stream) {
    const float* x    = (const float*)d_in[0];
    const float* gn_w = (const float*)d_in[1];
    const float* gn_b = (const float*)d_in[2];
    const float* w_in = (const float*)d_in[3];
    const float* s_in = (const float*)d_in[4];
    const float* b_in = (const float*)d_in[5];
    const float* w_k  = (const float*)d_in[6];
    const float* s_k  = (const float*)d_in[7];
    const float* b_k  = (const float*)d_in[8];
    const float* w_v  = (const float*)d_in[9];
    const float* s_v  = (const float*)d_in[10];
    const float* b_v  = (const float*)d_in[11];
    const float* w_out= (const float*)d_in[12];
    const float* s_out= (const float*)d_in[13];
    const float* b_out= (const float*)d_in[14];
    const float* w1   = (const float*)d_in[15];
    const float* s1   = (const float*)d_in[16];
    const float* b1   = (const float*)d_in[17];
    const float* w2   = (const float*)d_in[18];
    const float* s2   = (const float*)d_in[19];
    const float* b2   = (const float*)d_in[20];
    float* out = (float*)d_out;
    float* ws = (float*)d_ws;

    float* part = ws;                           // 2048
    float* Aarr = ws + 2048;
    float* Barr = ws + 6144;                    // end 10240
    unsigned short* tcl = (unsigned short*)(ws + 10240);       // 12,582,912 f -> end 12,593,152
    unsigned short* xb   = (unsigned short*)(ws + 12593152);
    unsigned short* x1cl = (unsigned short*)(ws + 12593152);
    unsigned short* apx  = (unsigned short*)(ws + 20981760);
    unsigned short* hcl  = (unsigned short*)(ws + 20981760);   // 33,554,432 sh -> end 37,758,976
    unsigned short* kd_t = (unsigned short*)(ws + 37758976);
    unsigned short* vd_b = (unsigned short*)(ws + 38283264);
    unsigned short* wb2  = (unsigned short*)(ws + 39331840);
    unsigned short* wob  = (unsigned short*)(ws + 39774208);
    unsigned short* w1b  = (unsigned short*)(ws + 39806976);
    unsigned short* w2b  = (unsigned short*)(ws + 39872512);

    gn_part_kernel<<<dim3(64, 16), 256, 0, stream>>>(x, part);
    gn_final_kernel<<<16, 256, 0, stream>>>(part, gn_w, gn_b, Aarr, Barr);
    xnb_kernel<<<dim3(64, 16), 256, 0, stream>>>(x, Aarr, Barr, xb);
    wcvt_kernel<<<4736, 256, 0, stream>>>(w_in, w_out, w1, w2, wb2, wob, w1b, w2b);
    conv3_mfma_kernel<<<768, 256, 0, stream>>>(xb, wb2, s_in, b_in, tcl);
    dw_kernel<<<dim3(16, 16), 256, 0, stream>>>(tcl, w_k, s_k, b_k, w_v, s_v, b_v, kd_t, vd_b);
    attn_mfma_kernel<<<dim3(64, 16), 256, 0, stream>>>(tcl, kd_t, vd_b, apx);
    catconv_mfma_kernel<<<dim3(16, 4, 16), 256, 0, stream>>>(apx, tcl, wob, x, s_out, b_out, out, x1cl);
    ffn1_mfma_kernel<<<dim3(16, 8, 16), 256, 0, stream>>>(x1cl, w1b, s1, b1, hcl);
    ffn2_mfma_kernel<<<dim3(16, 4, 16), 256, 0, stream>>>(hcl, w2b, s2, b2, out);
}